// Round 5
// baseline (297.634 us; speedup 1.0000x reference)
//
#include <hip/hip_runtime.h>
#include <stdint.h>

#define N_TOK 16384
#define DDIM  1024
#define NEXP  8
#define CNT_STRIDE 64   // pad each counter to its own 256B line

#define BM 128
#define BN 128
#define BK 64
#define NKT 16          // DDIM / BK
#define MAX_TILES 264   // sum ceil(cnt_e/128) <= 32768/128 + 8
#define EP_PITCH 72     // epilogue LDS row pitch in ushorts (144B: 16B-aligned, bank-spread)

typedef __bf16 bf16x8 __attribute__((ext_vector_type(8)));
typedef float  f32x4  __attribute__((ext_vector_type(4)));

__device__ __forceinline__ unsigned short f2bf(float f) {
  union { float f; uint32_t u; } a; a.f = f;
  uint32_t u = a.u;
  u += 0x7fffu + ((u >> 16) & 1u);   // RNE
  return (unsigned short)(u >> 16);
}

__device__ __forceinline__ float bf2f(unsigned short u) {
  union { uint32_t u; float f; } a; a.u = ((uint32_t)u) << 16;
  return a.f;
}

__device__ __forceinline__ float2 bfpair(uint32_t u) {
  union { uint32_t u; float f; } lo, hi;
  lo.u = u << 16; hi.u = u & 0xffff0000u;
  return make_float2(lo.f, hi.f);
}

__device__ __forceinline__ void load_lds16(const void* g, void* l) {
  __builtin_amdgcn_global_load_lds(
      (const __attribute__((address_space(1))) void*)g,
      (__attribute__((address_space(3))) void*)l,
      16, 0, 0);
}

#define SCHED_FENCE() __builtin_amdgcn_sched_barrier(0)
#define BAR_PLAIN() do { SCHED_FENCE(); asm volatile("s_barrier" ::: "memory"); SCHED_FENCE(); } while (0)
#define BAR_VM0()   do { SCHED_FENCE(); asm volatile("s_waitcnt vmcnt(0)\n\ts_barrier" ::: "memory"); SCHED_FENCE(); } while (0)

// ---- router: logits, softmax, top2, block-aggregated binning, loss partials,
//      x->bf16 cast, and fused expert_w->bf16 cast (overlaps the 100 MB ew
//      stream under router compute — measured better than a split cast kernel).
// 512 thr = 8 waves x 4 tokens; grid 512 blocks (32 tokens/block).
// Dim-major batched: the wave's 4 tokens share each rw chunk load; float4
// x-loads + uint2 packed xg stores.
__global__ __launch_bounds__(512) void router_kernel(
    const float* __restrict__ x, const float* __restrict__ rw,
    const float* __restrict__ rb, const float* __restrict__ cv,
    const float* __restrict__ cwp,
    const float4* __restrict__ ew4, ushort4* __restrict__ wb4,
    unsigned short* __restrict__ xg,
    int* __restrict__ perm_idx, float* __restrict__ perm_w,
    int* __restrict__ inv_idx,
    int* __restrict__ cnt, float* __restrict__ sum_w)
{
  __shared__ int   sCnt[NEXP];
  __shared__ int   sBase[NEXP];
  __shared__ float sSW[NEXP];
  __shared__ int   sE0[32], sE1[32], sR0[32], sR1[32];
  __shared__ float sW0[32], sW1[32];

  const int tid = threadIdx.x;
  if (tid < NEXP) { sCnt[tid] = 0; sSW[tid] = 0.0f; }
  __syncthreads();

  const int wave = tid >> 6;     // 0..7
  const int lane = tid & 63;
  const int n0 = blockIdx.x * 32 + wave * 4;   // this wave's 4 tokens

  const float cw = cwp[0];
  const float4* rw4 = (const float4*)rw;       // [e*256 + dp]

  const float4* x4[4];
  uint2* xgp[4];
#pragma unroll
  for (int t = 0; t < 4; ++t) {
    x4[t]  = (const float4*)(x + (size_t)(n0 + t) * DDIM);
    xgp[t] = (uint2*)(xg + (size_t)(n0 + t) * DDIM);
  }

  float p[4][NEXP];
#pragma unroll
  for (int t = 0; t < 4; ++t)
#pragma unroll
    for (int e = 0; e < NEXP; ++e) p[t][e] = 0.0f;

#pragma unroll
  for (int it = 0; it < 4; ++it) {
    const int dp = lane + 64 * it;             // float4 index (256 per row)
    float4 wv[NEXP];
#pragma unroll
    for (int e = 0; e < NEXP; ++e) wv[e] = rw4[e * 256 + dp];
#pragma unroll
    for (int t = 0; t < 4; ++t) {
      float4 xv = x4[t][dp];
      uint2 pk;
      pk.x = (uint32_t)f2bf(xv.x) | ((uint32_t)f2bf(xv.y) << 16);
      pk.y = (uint32_t)f2bf(xv.z) | ((uint32_t)f2bf(xv.w) << 16);
      xgp[t][dp] = pk;
#pragma unroll
      for (int e = 0; e < NEXP; ++e)
        p[t][e] = fmaf(xv.x, wv[e].x,
                  fmaf(xv.y, wv[e].y,
                  fmaf(xv.z, wv[e].z,
                  fmaf(xv.w, wv[e].w, p[t][e]))));
    }
  }

#pragma unroll
  for (int t = 0; t < 4; ++t)
#pragma unroll
    for (int e = 0; e < NEXP; ++e) {
#pragma unroll
      for (int off = 32; off > 0; off >>= 1)
        p[t][e] += __shfl_xor(p[t][e], off, 64);
    }

  float lsw[NEXP];
#pragma unroll
  for (int e = 0; e < NEXP; ++e) lsw[e] = 0.0f;

#pragma unroll
  for (int t = 0; t < 4; ++t) {
    const int i = wave * 4 + t;                // token slot in block (0..31)
    if (lane == 0) {
      float w[NEXP];
      float m = -1e30f;
#pragma unroll
      for (int e = 0; e < NEXP; ++e) {
        w[e] = p[t][e] + rb[e] + cw * cv[e];
        m = fmaxf(m, w[e]);
      }
      float s = 0.0f;
#pragma unroll
      for (int e = 0; e < NEXP; ++e) { w[e] = expf(w[e] - m); s += w[e]; }
      float inv = 1.0f / s;
#pragma unroll
      for (int e = 0; e < NEXP; ++e) { w[e] *= inv; lsw[e] += w[e]; }
      int e0 = 0;
#pragma unroll
      for (int e = 1; e < NEXP; ++e) if (w[e] > w[e0]) e0 = e;
      int e1 = (e0 == 0) ? 1 : 0;
#pragma unroll
      for (int e = 0; e < NEXP; ++e) if (e != e0 && w[e] > w[e1]) e1 = e;
      float rsum = 1.0f / (w[e0] + w[e1]);
      int r0 = atomicAdd(&sCnt[e0], 1);
      int r1 = atomicAdd(&sCnt[e1], 1);
      sE0[i] = e0; sE1[i] = e1; sR0[i] = r0; sR1[i] = r1;
      sW0[i] = w[e0] * rsum; sW1[i] = w[e1] * rsum;
    }
  }

  if (lane == 0) {
#pragma unroll
    for (int e = 0; e < NEXP; ++e) atomicAdd(&sSW[e], lsw[e]);
  }
  __syncthreads();

  if (tid < NEXP) {
    sBase[tid] = atomicAdd(&cnt[tid * CNT_STRIDE], sCnt[tid]);
    atomicAdd(&sum_w[tid * CNT_STRIDE], sSW[tid]);
  }
  __syncthreads();

  if (tid < 64) {
    int i = tid >> 1, k = tid & 1;
    int e = k ? sE1[i] : sE0[i];
    int r = k ? sR1[i] : sR0[i];
    float wv = k ? sW1[i] : sW0[i];
    int pos = sBase[e] + r;
    int n = blockIdx.x * 32 + i;
    perm_idx[e * N_TOK + pos] = n;
    perm_w [e * N_TOK + pos] = wv;
    inv_idx[2 * n + k] = (e << 14) | pos;     // pos < 16384 fits 14 bits
  }

  // fused expert_w fp32->bf16 cast: E*D*D/4 = 2,097,152 float4 over
  // 512 blocks x 512 threads = 262,144 threads -> exactly 8 each.
  size_t base = (size_t)blockIdx.x * 512 + tid;
#pragma unroll
  for (int i2 = 0; i2 < 8; ++i2) {
    size_t idx = base + (size_t)i2 * 262144;
    float4 v = ew4[idx];
    wb4[idx] = make_ushort4(f2bf(v.x), f2bf(v.y), f2bf(v.z), f2bf(v.w));
  }
}

// ---- grouped GEMM, 128x128 tile, BK=64, 4 waves, double-buffered LDS,
//      2-phase pipeline (issue ALL of tile t+1's staging at the top of tile t;
//      one vmcnt(0)+s_barrier per K-tile), sized for 2 blocks/CU:
//      LDS = 64KB staging + 1KB tok/wt -> two co-resident blocks per CU, so
//      one block's barrier drain overlaps the other block's MFMA (m114
//      implicit cross-block overlap — the mechanism behind m97's 3-block/CU).
// Addressing/swizzle/epilogue identical to the verified 128² kernel (R0);
// schedule identical to the verified 2-phase dbuf kernel (R2).
// Flat grid of MAX_TILES*8 blocks; id = tileIdx + MAX_TILES*tn so the 8
// tn-blocks sharing one A-tile have ids congruent mod 8 (264%8==0) -> same XCD.
template<int MODE>
__global__ __launch_bounds__(256, 2) void moe_gemm_kernel(
    const unsigned short* __restrict__ xg, const unsigned short* __restrict__ wb,
    const float* __restrict__ eb,
    const int* __restrict__ perm_idx, const float* __restrict__ perm_w,
    const int* __restrict__ cnt,
    unsigned short* __restrict__ ybuf, float* __restrict__ out)
{
  const int id = blockIdx.x;
  const int tn = id / MAX_TILES;
  const int tileIdx = id - tn * MAX_TILES;

  int e = -1, tm = 0, count = 0, ebase = 0, pref = 0;
#pragma unroll
  for (int j = 0; j < NEXP; ++j) {
    int c = cnt[j * CNT_STRIDE];
    int t = (c + BM - 1) >> 7;
    if (e < 0 && tileIdx < pref + t) { e = j; tm = tileIdx - pref; count = c; }
    if (e < 0) ebase += c;
    pref += t;
  }
  if (e < 0) return;

  __shared__ union {
    struct { __bf16 As[2][BM * BK]; __bf16 Bs[2][BN * BK]; } g;  // 32KB + 32KB
    __bf16 ep[4 * 64 * EP_PITCH];                                // 36,864B
  } sm;
  __shared__ int   tokS[BM];
  __shared__ float wtS[BM];

  const int tid = threadIdx.x;
  const int wave = tid >> 6;     // 0..3
  const int lane = tid & 63;

  if (tid < BM) {
    int row = tm * BM + tid;
    int rc = row < count ? row : count - 1;
    tokS[tid] = perm_idx[e * N_TOK + rc];
    wtS[tid] = (row < count) ? perm_w[e * N_TOK + row] : 0.0f;
  }
  __syncthreads();

  // staging: wave covers 32 rows (4 calls x 8 rows). lane -> row wave*32+t*8+(l>>3),
  // slot s=l&7; LDS[r][s] holds global chunk s^(r&7)  (chunk = 16B of the 128B row).
  const unsigned short* wbase = wb + (size_t)e * DDIM * DDIM;
  const unsigned short* aptr[4];
  const unsigned short* bptr[4];
#pragma unroll
  for (int t = 0; t < 4; ++t) {
    int r = wave * 32 + t * 8 + (lane >> 3);
    int cg = (lane & 7) ^ (r & 7);
    aptr[t] = xg + (size_t)tokS[r] * DDIM + cg * 8;
    bptr[t] = wbase + (size_t)(tn * BN + r) * DDIM + cg * 8;
  }

#define STG_ALL(bsel) do { \
    _Pragma("unroll") \
    for (int t4 = 0; t4 < 4; ++t4) { \
      load_lds16(aptr[t4], &sm.g.As[bsel][(wave * 32 + t4 * 8) * BK]); \
      load_lds16(bptr[t4], &sm.g.Bs[bsel][(wave * 32 + t4 * 8) * BK]); \
      aptr[t4] += BK; bptr[t4] += BK; \
    } \
  } while (0)

  // prologue: stage tile 0 into buf 0, full drain once.
  STG_ALL(0);
  BAR_VM0();

  const int mw = (wave >> 1) * 64;
  const int nw = (wave & 1) * 64;
  const int quad = lane >> 4;
  const int l15 = lane & 15;

  f32x4 acc[4][4] = {};   // acc[mi][ni]: rows mw+mi*16+l15, cols nw+ni*16+quad*4+reg

#pragma unroll
  for (int kt = 0; kt < NKT; ++kt) {
    const int b = kt & 1, nb = b ^ 1;
    const __bf16* Ab = sm.g.As[b];
    const __bf16* Bb = sm.g.Bs[b];

    // issue ALL of tile kt+1's staging up front (8 gload_lds/thread) — these
    // have the entire compute of tile kt to land under.
    if (kt + 1 < NKT) STG_ALL(nb);

#pragma unroll
    for (int ks = 0; ks < 2; ++ks) {
      bf16x8 af[4], bfr[4];
#pragma unroll
      for (int mi = 0; mi < 4; ++mi) {
        int m = mw + mi * 16 + l15;
        int slot = (ks * 4 + quad) ^ (m & 7);
        af[mi] = *(const bf16x8*)&Ab[m * BK + slot * 8];
      }
#pragma unroll
      for (int ni = 0; ni < 4; ++ni) {
        int n = nw + ni * 16 + l15;
        int slot = (ks * 4 + quad) ^ (n & 7);
        bfr[ni] = *(const bf16x8*)&Bb[n * BK + slot * 8];
      }
#pragma unroll
      for (int mi = 0; mi < 4; ++mi)
#pragma unroll
        for (int ni = 0; ni < 4; ++ni)
          // swapped operands: D^T -> l15 indexes token row, quad*4+reg indexes col
          acc[mi][ni] = __builtin_amdgcn_mfma_f32_16x16x32_bf16(bfr[ni], af[mi], acc[mi][ni], 0, 0, 0);
    }

    // one barrier per K-tile: tile kt+1's loads were issued a full tile ago ->
    // vmcnt(0) is a cheap drain of (almost always) already-landed loads.
    if (kt + 1 < NKT) BAR_VM0();
    else             BAR_PLAIN();   // after final tile: LDS reusable for epilogue
  }

#undef STG_ALL

  const int valid = count - tm * BM;
  const int gb = ebase + tm * BM;

  if (MODE == 1) {
    // repack through per-wave LDS slab, then fully-coalesced 16B stores
    __bf16* slab = &sm.ep[wave * (64 * EP_PITCH)];
#pragma unroll
    for (int mi = 0; mi < 4; ++mi) {
      float wt = wtS[mw + mi * 16 + l15];
#pragma unroll
      for (int ni = 0; ni < 4; ++ni) {
        int gcol = tn * BN + nw + ni * 16 + quad * 4;
        const float4 bv = *(const float4*)&eb[e * DDIM + gcol];
        ushort4 pk;
        pk.x = f2bf((acc[mi][ni][0] + bv.x) * wt);
        pk.y = f2bf((acc[mi][ni][1] + bv.y) * wt);
        pk.z = f2bf((acc[mi][ni][2] + bv.z) * wt);
        pk.w = f2bf((acc[mi][ni][3] + bv.w) * wt);
        *(ushort4*)&slab[(mi * 16 + l15) * EP_PITCH + ni * 16 + quad * 4] = pk;
      }
    }
#pragma unroll
    for (int s = 0; s < 8; ++s) {
      int lrow = s * 8 + (lane >> 3);
      uint4 v = *(const uint4*)&slab[lrow * EP_PITCH + (lane & 7) * 8];
      int brow = mw + lrow;
      if (brow < valid)
        *(uint4*)&ybuf[(size_t)(gb + brow) * DDIM + tn * BN + nw + (lane & 7) * 8] = v;
    }
  } else {
    // atomic fallback (small-ws path)
#pragma unroll
    for (int mi = 0; mi < 4; ++mi) {
      int brow = mw + mi * 16 + l15;
      float wt = wtS[brow];
      int tok = tokS[brow];
#pragma unroll
      for (int ni = 0; ni < 4; ++ni) {
        int gcol = tn * BN + nw + ni * 16 + quad * 4;
        const float4 bv = *(const float4*)&eb[e * DDIM + gcol];
        if (brow < valid) {
          atomicAdd(out + (size_t)tok * DDIM + gcol + 0, (acc[mi][ni][0] + bv.x) * wt);
          atomicAdd(out + (size_t)tok * DDIM + gcol + 1, (acc[mi][ni][1] + bv.y) * wt);
          atomicAdd(out + (size_t)tok * DDIM + gcol + 2, (acc[mi][ni][2] + bv.z) * wt);
          atomicAdd(out + (size_t)tok * DDIM + gcol + 3, (acc[mi][ni][3] + bv.w) * wt);
        }
      }
    }
  }
}

// ---- combine: out[n] = y[g0] + y[g1] (weights+bias already folded) ----
__global__ __launch_bounds__(256) void combine_kernel(
    const unsigned short* __restrict__ ybuf, const int* __restrict__ inv_idx,
    const int* __restrict__ cnt, float* __restrict__ out)
{
  const int wave = threadIdx.x >> 6;
  const int lane = threadIdx.x & 63;
  const int n = blockIdx.x * 4 + wave;

  int base[NEXP];
  int acc = 0;
#pragma unroll
  for (int j = 0; j < NEXP; ++j) { base[j] = acc; acc += cnt[j * CNT_STRIDE]; }

  int i0 = inv_idx[2 * n];
  int i1 = inv_idx[2 * n + 1];
  int g0 = base[i0 >> 14] + (i0 & 16383);
  int g1 = base[i1 >> 14] + (i1 & 16383);

  const uint4* r0 = (const uint4*)(ybuf + (size_t)g0 * DDIM);
  const uint4* r1 = (const uint4*)(ybuf + (size_t)g1 * DDIM);
  float4* o = (float4*)(out + (size_t)n * DDIM);

#pragma unroll
  for (int it = 0; it < 2; ++it) {
    int c = lane + 64 * it;
    uint4 a = r0[c];
    uint4 b = r1[c];
    float2 a0 = bfpair(a.x), a1 = bfpair(a.y), a2 = bfpair(a.z), a3 = bfpair(a.w);
    float2 b0 = bfpair(b.x), b1 = bfpair(b.y), b2 = bfpair(b.z), b3 = bfpair(b.w);
    float4 v0, v1;
    v0.x = a0.x + b0.x; v0.y = a0.y + b0.y; v0.z = a1.x + b1.x; v0.w = a1.y + b1.y;
    v1.x = a2.x + b2.x; v1.y = a2.y + b2.y; v1.z = a3.x + b3.x; v1.w = a3.y + b3.y;
    o[2 * c] = v0;
    o[2 * c + 1] = v1;
  }
}

__global__ void loss_kernel(const float* __restrict__ sum_w,
                            const int* __restrict__ cnt,
                            float* __restrict__ out) {
  if (threadIdx.x == 0 && blockIdx.x == 0) {
    float l = 0.0f;
#pragma unroll
    for (int e = 0; e < NEXP; ++e)
      l += sum_w[e * CNT_STRIDE] * (float)cnt[e * CNT_STRIDE];
    out[(size_t)N_TOK * DDIM] = l * (1.0f / ((float)N_TOK * (float)N_TOK));
  }
}

extern "C" void kernel_launch(void* const* d_in, const int* in_sizes, int n_in,
                              void* d_out, int out_size, void* d_ws, size_t ws_size,
                              hipStream_t stream) {
  const float* x  = (const float*)d_in[0];
  const float* cv = (const float*)d_in[1];
  const float* rw = (const float*)d_in[2];
  const float* rb = (const float*)d_in[3];
  const float* ew = (const float*)d_in[4];
  const float* eb = (const float*)d_in[5];
  const float* cw = (const float*)d_in[6];
  float* out = (float*)d_out;

  char* ws = (char*)d_ws;
  unsigned short* xg = (unsigned short*)ws;                       // N*D bf16   (33,554,432 B)
  unsigned short* wb = (unsigned short*)(ws + 33554432);          // E*D*D bf16 (16,777,216 B)
  int*   perm_idx = (int*)  (ws + 50331648);                      // E*N int    (524,288 B)
  float* perm_w   = (float*)(ws + 50855936);                      // E*N float  (524,288 B)
  int*   inv_idx  = (int*)  (ws + 51380224);                      // 2*N int    (131,072 B)
  int*   cnt      = (int*)  (ws + 51511296);                      // padded     (2,048 B)
  float* sum_w    = (float*)(ws + 51513344);                      // padded     (2,048 B)
  unsigned short* ybuf = (unsigned short*)(ws + 51515392);        // 2*N*D bf16 (67,108,864 B)
  const size_t NEED = 51515392ull + 67108864ull;

  const bool big = ws_size >= NEED;

  hipMemsetAsync(cnt, 0, 4096, stream);                           // cnt + sum_w (padded)
  if (!big)
    hipMemsetAsync(d_out, 0, (size_t)N_TOK * DDIM * sizeof(float), stream);

  router_kernel<<<N_TOK / 32, 512, 0, stream>>>(x, rw, rb, cv, cw,
                                                (const float4*)ew, (ushort4*)wb,
                                                xg, perm_idx, perm_w, inv_idx, cnt, sum_w);

  if (big) {
    moe_gemm_kernel<1><<<MAX_TILES * 8, 256, 0, stream>>>(
        xg, wb, eb, perm_idx, perm_w, cnt, ybuf, out);
    combine_kernel<<<N_TOK / 4, 256, 0, stream>>>(ybuf, inv_idx, cnt, out);
  } else {
    moe_gemm_kernel<0><<<MAX_TILES * 8, 256, 0, stream>>>(
        xg, wb, eb, perm_idx, perm_w, cnt, ybuf, out);
  }

  loss_kernel<<<1, 64, 0, stream>>>(sum_w, cnt, out);
}

// Round 6
// 281.547 us; speedup vs baseline: 1.0571x; 1.0571x over previous
//
#include <hip/hip_runtime.h>
#include <stdint.h>

#define N_TOK 16384
#define DDIM  1024
#define NEXP  8
#define CNT_STRIDE 64   // pad each counter to its own 256B line

#define BM 256
#define BN 256
#define BK 64
#define NKT 16          // DDIM / BK
#define MAX_TILES 136   // sum ceil(cnt_e/256) <= 32768/256 + 8
#define EP_PITCH 72     // epilogue LDS row pitch in ushorts (144B: 16B-aligned, bank-spread)

typedef __bf16 bf16x8 __attribute__((ext_vector_type(8)));
typedef float  f32x4  __attribute__((ext_vector_type(4)));

__device__ __forceinline__ unsigned short f2bf(float f) {
  union { float f; uint32_t u; } a; a.f = f;
  uint32_t u = a.u;
  u += 0x7fffu + ((u >> 16) & 1u);   // RNE
  return (unsigned short)(u >> 16);
}

__device__ __forceinline__ float bf2f(unsigned short u) {
  union { uint32_t u; float f; } a; a.u = ((uint32_t)u) << 16;
  return a.f;
}

__device__ __forceinline__ float2 bfpair(uint32_t u) {
  union { uint32_t u; float f; } lo, hi;
  lo.u = u << 16; hi.u = u & 0xffff0000u;
  return make_float2(lo.f, hi.f);
}

__device__ __forceinline__ void load_lds16(const void* g, void* l) {
  __builtin_amdgcn_global_load_lds(
      (const __attribute__((address_space(1))) void*)g,
      (__attribute__((address_space(3))) void*)l,
      16, 0, 0);
}

#define SCHED_FENCE() __builtin_amdgcn_sched_barrier(0)
#define BAR_PLAIN() do { SCHED_FENCE(); asm volatile("s_barrier" ::: "memory"); SCHED_FENCE(); } while (0)
#define BAR_VM0()   do { SCHED_FENCE(); asm volatile("s_waitcnt vmcnt(0)\n\ts_barrier" ::: "memory"); SCHED_FENCE(); } while (0)

// ---- router: logits, softmax, top2, block-aggregated binning, loss partials,
//      x->bf16 cast, and fused expert_w->bf16 cast (overlaps the 100 MB ew
//      stream under router compute).
// 512 thr = 8 waves x 4 tokens; grid 512 blocks (32 tokens/block).
// Dim-major batched: the wave's 4 tokens share each rw chunk load; float4
// x-loads + uint2 packed xg stores.
__global__ __launch_bounds__(512) void router_kernel(
    const float* __restrict__ x, const float* __restrict__ rw,
    const float* __restrict__ rb, const float* __restrict__ cv,
    const float* __restrict__ cwp,
    const float4* __restrict__ ew4, ushort4* __restrict__ wb4,
    unsigned short* __restrict__ xg,
    int* __restrict__ perm_idx, float* __restrict__ perm_w,
    int* __restrict__ inv_idx,
    int* __restrict__ cnt, float* __restrict__ sum_w)
{
  __shared__ int   sCnt[NEXP];
  __shared__ int   sBase[NEXP];
  __shared__ float sSW[NEXP];
  __shared__ int   sE0[32], sE1[32], sR0[32], sR1[32];
  __shared__ float sW0[32], sW1[32];

  const int tid = threadIdx.x;
  if (tid < NEXP) { sCnt[tid] = 0; sSW[tid] = 0.0f; }
  __syncthreads();

  const int wave = tid >> 6;     // 0..7
  const int lane = tid & 63;
  const int n0 = blockIdx.x * 32 + wave * 4;   // this wave's 4 tokens

  const float cw = cwp[0];
  const float4* rw4 = (const float4*)rw;       // [e*256 + dp]

  const float4* x4[4];
  uint2* xgp[4];
#pragma unroll
  for (int t = 0; t < 4; ++t) {
    x4[t]  = (const float4*)(x + (size_t)(n0 + t) * DDIM);
    xgp[t] = (uint2*)(xg + (size_t)(n0 + t) * DDIM);
  }

  float p[4][NEXP];
#pragma unroll
  for (int t = 0; t < 4; ++t)
#pragma unroll
    for (int e = 0; e < NEXP; ++e) p[t][e] = 0.0f;

#pragma unroll
  for (int it = 0; it < 4; ++it) {
    const int dp = lane + 64 * it;             // float4 index (256 per row)
    float4 wv[NEXP];
#pragma unroll
    for (int e = 0; e < NEXP; ++e) wv[e] = rw4[e * 256 + dp];
#pragma unroll
    for (int t = 0; t < 4; ++t) {
      float4 xv = x4[t][dp];
      uint2 pk;
      pk.x = (uint32_t)f2bf(xv.x) | ((uint32_t)f2bf(xv.y) << 16);
      pk.y = (uint32_t)f2bf(xv.z) | ((uint32_t)f2bf(xv.w) << 16);
      xgp[t][dp] = pk;
#pragma unroll
      for (int e = 0; e < NEXP; ++e)
        p[t][e] = fmaf(xv.x, wv[e].x,
                  fmaf(xv.y, wv[e].y,
                  fmaf(xv.z, wv[e].z,
                  fmaf(xv.w, wv[e].w, p[t][e]))));
    }
  }

#pragma unroll
  for (int t = 0; t < 4; ++t)
#pragma unroll
    for (int e = 0; e < NEXP; ++e) {
#pragma unroll
      for (int off = 32; off > 0; off >>= 1)
        p[t][e] += __shfl_xor(p[t][e], off, 64);
    }

  float lsw[NEXP];
#pragma unroll
  for (int e = 0; e < NEXP; ++e) lsw[e] = 0.0f;

#pragma unroll
  for (int t = 0; t < 4; ++t) {
    const int i = wave * 4 + t;                // token slot in block (0..31)
    if (lane == 0) {
      float w[NEXP];
      float m = -1e30f;
#pragma unroll
      for (int e = 0; e < NEXP; ++e) {
        w[e] = p[t][e] + rb[e] + cw * cv[e];
        m = fmaxf(m, w[e]);
      }
      float s = 0.0f;
#pragma unroll
      for (int e = 0; e < NEXP; ++e) { w[e] = expf(w[e] - m); s += w[e]; }
      float inv = 1.0f / s;
#pragma unroll
      for (int e = 0; e < NEXP; ++e) { w[e] *= inv; lsw[e] += w[e]; }
      int e0 = 0;
#pragma unroll
      for (int e = 1; e < NEXP; ++e) if (w[e] > w[e0]) e0 = e;
      int e1 = (e0 == 0) ? 1 : 0;
#pragma unroll
      for (int e = 0; e < NEXP; ++e) if (e != e0 && w[e] > w[e1]) e1 = e;
      float rsum = 1.0f / (w[e0] + w[e1]);
      int r0 = atomicAdd(&sCnt[e0], 1);
      int r1 = atomicAdd(&sCnt[e1], 1);
      sE0[i] = e0; sE1[i] = e1; sR0[i] = r0; sR1[i] = r1;
      sW0[i] = w[e0] * rsum; sW1[i] = w[e1] * rsum;
    }
  }

  if (lane == 0) {
#pragma unroll
    for (int e = 0; e < NEXP; ++e) atomicAdd(&sSW[e], lsw[e]);
  }
  __syncthreads();

  if (tid < NEXP) {
    sBase[tid] = atomicAdd(&cnt[tid * CNT_STRIDE], sCnt[tid]);
    atomicAdd(&sum_w[tid * CNT_STRIDE], sSW[tid]);
  }
  __syncthreads();

  if (tid < 64) {
    int i = tid >> 1, k = tid & 1;
    int e = k ? sE1[i] : sE0[i];
    int r = k ? sR1[i] : sR0[i];
    float wv = k ? sW1[i] : sW0[i];
    int pos = sBase[e] + r;
    int n = blockIdx.x * 32 + i;
    perm_idx[e * N_TOK + pos] = n;
    perm_w [e * N_TOK + pos] = wv;
    inv_idx[2 * n + k] = (e << 14) | pos;     // pos < 16384 fits 14 bits
  }

  // fused expert_w fp32->bf16 cast: E*D*D/4 = 2,097,152 float4 over
  // 512 blocks x 512 threads = 262,144 threads -> exactly 8 each.
  size_t base = (size_t)blockIdx.x * 512 + tid;
#pragma unroll
  for (int i2 = 0; i2 < 8; ++i2) {
    size_t idx = base + (size_t)i2 * 262144;
    float4 v = ew4[idx];
    wb4[idx] = make_ushort4(f2bf(v.x), f2bf(v.y), f2bf(v.z), f2bf(v.w));
  }
}

// ---- grouped GEMM, 256x256 tile, BK=64, 8 waves, double-buffered LDS,
//      2-phase pipeline: issue ALL of tile t+1's staging at the top of tile t
//      (issue-to-wait distance = one full compute tile >= LLC latency), zero
//      mid-tile barriers, one vmcnt(0)+s_barrier per K-tile.
// (best-measured GEMM configuration — R2 session: 104 us / ~660 TF)
// Flat grid of MAX_TILES*4 blocks; id = tileIdx + MAX_TILES*tn so the 4
// tn-blocks sharing one A-tile have ids congruent mod 8 (136%8==0) -> same XCD.
template<int MODE>
__global__ __launch_bounds__(512, 2) void moe_gemm_kernel(
    const unsigned short* __restrict__ xg, const unsigned short* __restrict__ wb,
    const float* __restrict__ eb,
    const int* __restrict__ perm_idx, const float* __restrict__ perm_w,
    const int* __restrict__ cnt,
    unsigned short* __restrict__ ybuf, float* __restrict__ out)
{
  const int id = blockIdx.x;
  const int tn = id / MAX_TILES;
  const int tileIdx = id - tn * MAX_TILES;

  int e = -1, tm = 0, count = 0, ebase = 0, pref = 0;
#pragma unroll
  for (int j = 0; j < NEXP; ++j) {
    int c = cnt[j * CNT_STRIDE];
    int t = (c + BM - 1) >> 8;
    if (e < 0 && tileIdx < pref + t) { e = j; tm = tileIdx - pref; count = c; }
    if (e < 0) ebase += c;
    pref += t;
  }
  if (e < 0) return;

  __shared__ union {
    struct { __bf16 As[2][BM * BK]; __bf16 Bs[2][BN * BK]; } g;  // 64KB + 64KB
    __bf16 ep[8 * 64 * EP_PITCH];                                // 73,728B
  } sm;
  __shared__ int   tokS[BM];
  __shared__ float wtS[BM];

  const int tid = threadIdx.x;
  const int wave = tid >> 6;     // 0..7
  const int lane = tid & 63;

  if (tid < BM) {
    int row = tm * BM + tid;
    int rc = row < count ? row : count - 1;
    tokS[tid] = perm_idx[e * N_TOK + rc];
    wtS[tid] = (row < count) ? perm_w[e * N_TOK + row] : 0.0f;
  }
  __syncthreads();

  // staging: each half (128 rows) covered as wave -> 16 rows (2 calls x 8 rows);
  // lane -> row base + (l>>3), chunk slot s = l&7; LDS[r][s] holds global
  // chunk s^(r&7) (chunk = 16B of the 128B row). r&7 == (lane>>3)&7 for all halves.
  const unsigned short* wbase = wb + (size_t)e * DDIM * DDIM;
  const int rl = wave * 16 + (lane >> 3);
  const int cg = (((lane & 7) ^ (lane >> 3)) & 7) * 8;

  const unsigned short* gA[2][2];
  const unsigned short* gB[2][2];
#pragma unroll
  for (int h = 0; h < 2; ++h)
#pragma unroll
    for (int j = 0; j < 2; ++j) {
      gA[h][j] = xg + (size_t)tokS[h * 128 + rl + j * 8] * DDIM + cg;
      gB[h][j] = wbase + (size_t)(tn * BN + h * 128 + rl + j * 8) * DDIM + cg;
    }

#define STG_A(h, bsel) do { \
    load_lds16(gA[h][0], &sm.g.As[bsel][((h) * 128 + wave * 16) * BK]);     gA[h][0] += BK; \
    load_lds16(gA[h][1], &sm.g.As[bsel][((h) * 128 + wave * 16 + 8) * BK]); gA[h][1] += BK; \
  } while (0)
#define STG_B(h, bsel) do { \
    load_lds16(gB[h][0], &sm.g.Bs[bsel][((h) * 128 + wave * 16) * BK]);     gB[h][0] += BK; \
    load_lds16(gB[h][1], &sm.g.Bs[bsel][((h) * 128 + wave * 16 + 8) * BK]); gB[h][1] += BK; \
  } while (0)

  // prologue: stage tile 0 into buf 0, full drain once.
  STG_A(0, 0); STG_A(1, 0); STG_B(0, 0); STG_B(1, 0);
  BAR_VM0();

  const int wr = wave >> 2;          // 0..1 -> 128-row slab
  const int wc = wave & 3;           // 0..3 -> 64-col slab
  const int quad = lane >> 4;
  const int l15 = lane & 15;
  // frag read: row r, k-slot slot = (ks*4+quad) ^ (r&7); r&7 == l15&7.
  const int sl0 = (quad ^ (l15 & 7)) * 8;              // ks=0 slot offset (elems)
  const int rowA = (wr * 128 + l15) * BK + sl0;        // ^32 flips to ks=1
  const int rowB = (wc * 64 + l15) * BK + sl0;

  f32x4 acc[8][4] = {};   // acc[mi][ni]: rows wr*128+mi*16+l15, cols wc*64+ni*16+quad*4+reg

#pragma unroll
  for (int t = 0; t < NKT; ++t) {
    const int b = t & 1, nb = b ^ 1;
    const __bf16* Ab = sm.g.As[b];
    const __bf16* Bb = sm.g.Bs[b];

    // issue ALL of tile t+1's staging up front (8 gload_lds/thread) — these
    // have the entire compute of tile t (24 ds_read + 64 MFMA/wave) to land.
    if (t + 1 < NKT) { STG_A(0, nb); STG_A(1, nb); STG_B(0, nb); STG_B(1, nb); }

    bf16x8 Bf[4][2];
#pragma unroll
    for (int ni = 0; ni < 4; ++ni)
#pragma unroll
      for (int ks = 0; ks < 2; ++ks)
        Bf[ni][ks] = *(const bf16x8*)&Bb[(rowB + ni * 1024) ^ (ks * 32)];

#pragma unroll
    for (int mi = 0; mi < 8; ++mi) {
      bf16x8 a0 = *(const bf16x8*)&Ab[(rowA + mi * 1024)];
      bf16x8 a1 = *(const bf16x8*)&Ab[(rowA + mi * 1024) ^ 32];
#pragma unroll
      for (int ni = 0; ni < 4; ++ni) {
        acc[mi][ni] = __builtin_amdgcn_mfma_f32_16x16x32_bf16(Bf[ni][0], a0, acc[mi][ni], 0, 0, 0);
        acc[mi][ni] = __builtin_amdgcn_mfma_f32_16x16x32_bf16(Bf[ni][1], a1, acc[mi][ni], 0, 0, 0);
      }
    }

    // one barrier per K-tile: tile t+1's loads were issued a full tile ago ->
    // vmcnt(0) is a cheap drain of (almost always) already-landed loads.
    if (t + 1 < NKT) BAR_VM0();
    else             BAR_PLAIN();   // after final tile: LDS reusable for epilogue
  }

#undef STG_A
#undef STG_B

  const int valid = count - tm * BM;
  const int gb = ebase + tm * BM;

  if (MODE == 1) {
    // repack through per-wave LDS slab (2 passes of 64 rows), then
    // fully-coalesced 16B stores.
    __bf16* slab = &sm.ep[wave * (64 * EP_PITCH)];
#pragma unroll
    for (int p = 0; p < 2; ++p) {
#pragma unroll
      for (int mi4 = 0; mi4 < 4; ++mi4) {
        const int mi = p * 4 + mi4;
        float wt = wtS[wr * 128 + mi * 16 + l15];
#pragma unroll
        for (int ni = 0; ni < 4; ++ni) {
          int gcol = tn * BN + wc * 64 + ni * 16 + quad * 4;
          const float4 bv = *(const float4*)&eb[e * DDIM + gcol];
          ushort4 pk;
          pk.x = f2bf((acc[mi][ni][0] + bv.x) * wt);
          pk.y = f2bf((acc[mi][ni][1] + bv.y) * wt);
          pk.z = f2bf((acc[mi][ni][2] + bv.z) * wt);
          pk.w = f2bf((acc[mi][ni][3] + bv.w) * wt);
          *(ushort4*)&slab[(mi4 * 16 + l15) * EP_PITCH + ni * 16 + quad * 4] = pk;
        }
      }
#pragma unroll
      for (int s = 0; s < 8; ++s) {
        int lrow = s * 8 + (lane >> 3);
        uint4 v = *(const uint4*)&slab[lrow * EP_PITCH + (lane & 7) * 8];
        int brow = wr * 128 + p * 64 + lrow;
        if (brow < valid)
          *(uint4*)&ybuf[(size_t)(gb + brow) * DDIM + tn * BN + wc * 64 + (lane & 7) * 8] = v;
      }
    }
  } else {
    // atomic fallback (small-ws path)
#pragma unroll
    for (int mi = 0; mi < 8; ++mi) {
      int brow = wr * 128 + mi * 16 + l15;
      float wt = wtS[brow];
      int tok = tokS[brow];
      if (brow < valid) {
#pragma unroll
        for (int ni = 0; ni < 4; ++ni) {
          int gcol = tn * BN + wc * 64 + ni * 16 + quad * 4;
          const float4 bv = *(const float4*)&eb[e * DDIM + gcol];
          atomicAdd(out + (size_t)tok * DDIM + gcol + 0, (acc[mi][ni][0] + bv.x) * wt);
          atomicAdd(out + (size_t)tok * DDIM + gcol + 1, (acc[mi][ni][1] + bv.y) * wt);
          atomicAdd(out + (size_t)tok * DDIM + gcol + 2, (acc[mi][ni][2] + bv.z) * wt);
          atomicAdd(out + (size_t)tok * DDIM + gcol + 3, (acc[mi][ni][3] + bv.w) * wt);
        }
      }
    }
  }
}

// ---- combine: out[n] = y[g0] + y[g1] (weights+bias already folded),
//      with the load-balancing loss fused into block 0 (one fewer dispatch).
__global__ __launch_bounds__(256) void combine_kernel(
    const unsigned short* __restrict__ ybuf, const int* __restrict__ inv_idx,
    const int* __restrict__ cnt, const float* __restrict__ sum_w,
    float* __restrict__ out)
{
  if (blockIdx.x == 0 && threadIdx.x == 0) {
    float l = 0.0f;
#pragma unroll
    for (int e = 0; e < NEXP; ++e)
      l += sum_w[e * CNT_STRIDE] * (float)cnt[e * CNT_STRIDE];
    out[(size_t)N_TOK * DDIM] = l * (1.0f / ((float)N_TOK * (float)N_TOK));
  }

  const int wave = threadIdx.x >> 6;
  const int lane = threadIdx.x & 63;
  const int n = blockIdx.x * 4 + wave;

  int base[NEXP];
  int acc = 0;
#pragma unroll
  for (int j = 0; j < NEXP; ++j) { base[j] = acc; acc += cnt[j * CNT_STRIDE]; }

  int i0 = inv_idx[2 * n];
  int i1 = inv_idx[2 * n + 1];
  int g0 = base[i0 >> 14] + (i0 & 16383);
  int g1 = base[i1 >> 14] + (i1 & 16383);

  const uint4* r0 = (const uint4*)(ybuf + (size_t)g0 * DDIM);
  const uint4* r1 = (const uint4*)(ybuf + (size_t)g1 * DDIM);
  float4* o = (float4*)(out + (size_t)n * DDIM);

#pragma unroll
  for (int it = 0; it < 2; ++it) {
    int c = lane + 64 * it;
    uint4 a = r0[c];
    uint4 b = r1[c];
    float2 a0 = bfpair(a.x), a1 = bfpair(a.y), a2 = bfpair(a.z), a3 = bfpair(a.w);
    float2 b0 = bfpair(b.x), b1 = bfpair(b.y), b2 = bfpair(b.z), b3 = bfpair(b.w);
    float4 v0, v1;
    v0.x = a0.x + b0.x; v0.y = a0.y + b0.y; v0.z = a1.x + b1.x; v0.w = a1.y + b1.y;
    v1.x = a2.x + b2.x; v1.y = a2.y + b2.y; v1.z = a3.x + b3.x; v1.w = a3.y + b3.y;
    o[2 * c] = v0;
    o[2 * c + 1] = v1;
  }
}

__global__ void loss_kernel(const float* __restrict__ sum_w,
                            const int* __restrict__ cnt,
                            float* __restrict__ out) {
  if (threadIdx.x == 0 && blockIdx.x == 0) {
    float l = 0.0f;
#pragma unroll
    for (int e = 0; e < NEXP; ++e)
      l += sum_w[e * CNT_STRIDE] * (float)cnt[e * CNT_STRIDE];
    out[(size_t)N_TOK * DDIM] = l * (1.0f / ((float)N_TOK * (float)N_TOK));
  }
}

extern "C" void kernel_launch(void* const* d_in, const int* in_sizes, int n_in,
                              void* d_out, int out_size, void* d_ws, size_t ws_size,
                              hipStream_t stream) {
  const float* x  = (const float*)d_in[0];
  const float* cv = (const float*)d_in[1];
  const float* rw = (const float*)d_in[2];
  const float* rb = (const float*)d_in[3];
  const float* ew = (const float*)d_in[4];
  const float* eb = (const float*)d_in[5];
  const float* cw = (const float*)d_in[6];
  float* out = (float*)d_out;

  char* ws = (char*)d_ws;
  unsigned short* xg = (unsigned short*)ws;                       // N*D bf16   (33,554,432 B)
  unsigned short* wb = (unsigned short*)(ws + 33554432);          // E*D*D bf16 (16,777,216 B)
  int*   perm_idx = (int*)  (ws + 50331648);                      // E*N int    (524,288 B)
  float* perm_w   = (float*)(ws + 50855936);                      // E*N float  (524,288 B)
  int*   inv_idx  = (int*)  (ws + 51380224);                      // 2*N int    (131,072 B)
  int*   cnt      = (int*)  (ws + 51511296);                      // padded     (2,048 B)
  float* sum_w    = (float*)(ws + 51513344);                      // padded     (2,048 B)
  unsigned short* ybuf = (unsigned short*)(ws + 51515392);        // 2*N*D bf16 (67,108,864 B)
  const size_t NEED = 51515392ull + 67108864ull;

  const bool big = ws_size >= NEED;

  hipMemsetAsync(cnt, 0, 4096, stream);                           // cnt + sum_w (padded)
  if (!big)
    hipMemsetAsync(d_out, 0, (size_t)N_TOK * DDIM * sizeof(float), stream);

  router_kernel<<<N_TOK / 32, 512, 0, stream>>>(x, rw, rb, cv, cw,
                                                (const float4*)ew, (ushort4*)wb,
                                                xg, perm_idx, perm_w, inv_idx, cnt, sum_w);

  if (big) {
    moe_gemm_kernel<1><<<MAX_TILES * 4, 512, 0, stream>>>(
        xg, wb, eb, perm_idx, perm_w, cnt, ybuf, out);
    combine_kernel<<<N_TOK / 4, 256, 0, stream>>>(ybuf, inv_idx, cnt, sum_w, out);
  } else {
    moe_gemm_kernel<0><<<MAX_TILES * 4, 512, 0, stream>>>(
        xg, wb, eb, perm_idx, perm_w, cnt, ybuf, out);
    loss_kernel<<<1, 64, 0, stream>>>(sum_w, cnt, out);
  }
}

// Round 7
// 279.845 us; speedup vs baseline: 1.0636x; 1.0061x over previous
//
#include <hip/hip_runtime.h>
#include <stdint.h>

#define N_TOK 16384
#define DDIM  1024
#define NEXP  8
#define CNT_STRIDE 64   // pad each counter to its own 256B line

#define BM 256
#define BN 256
#define BK 64
#define NKT 16          // DDIM / BK
#define MAX_TILES 136   // sum ceil(cnt_e/256) <= 32768/256 + 8

typedef __bf16 bf16x8 __attribute__((ext_vector_type(8)));
typedef float  f32x4  __attribute__((ext_vector_type(4)));

__device__ __forceinline__ unsigned short f2bf(float f) {
  union { float f; uint32_t u; } a; a.f = f;
  uint32_t u = a.u;
  u += 0x7fffu + ((u >> 16) & 1u);   // RNE
  return (unsigned short)(u >> 16);
}

__device__ __forceinline__ float bf2f(unsigned short u) {
  union { uint32_t u; float f; } a; a.u = ((uint32_t)u) << 16;
  return a.f;
}

__device__ __forceinline__ float2 bfpair(uint32_t u) {
  union { uint32_t u; float f; } lo, hi;
  lo.u = u << 16; hi.u = u & 0xffff0000u;
  return make_float2(lo.f, hi.f);
}

__device__ __forceinline__ void load_lds16(const void* g, void* l) {
  __builtin_amdgcn_global_load_lds(
      (const __attribute__((address_space(1))) void*)g,
      (__attribute__((address_space(3))) void*)l,
      16, 0, 0);
}

#define SCHED_FENCE() __builtin_amdgcn_sched_barrier(0)
#define BAR_PLAIN() do { SCHED_FENCE(); asm volatile("s_barrier" ::: "memory"); SCHED_FENCE(); } while (0)
#define BAR_VM0()   do { SCHED_FENCE(); asm volatile("s_waitcnt vmcnt(0)\n\ts_barrier" ::: "memory"); SCHED_FENCE(); } while (0)

// ---- router: logits, softmax, top2, block-aggregated binning, loss partials,
//      x->bf16 cast, and fused expert_w->bf16 cast (overlaps the 100 MB ew
//      stream under router compute).
// 512 thr = 8 waves x 4 tokens; grid 512 blocks (32 tokens/block).
__global__ __launch_bounds__(512) void router_kernel(
    const float* __restrict__ x, const float* __restrict__ rw,
    const float* __restrict__ rb, const float* __restrict__ cv,
    const float* __restrict__ cwp,
    const float4* __restrict__ ew4, ushort4* __restrict__ wb4,
    unsigned short* __restrict__ xg,
    int* __restrict__ perm_idx, float* __restrict__ perm_w,
    int* __restrict__ inv_idx,
    int* __restrict__ cnt, float* __restrict__ sum_w)
{
  __shared__ int   sCnt[NEXP];
  __shared__ int   sBase[NEXP];
  __shared__ float sSW[NEXP];
  __shared__ int   sE0[32], sE1[32], sR0[32], sR1[32];
  __shared__ float sW0[32], sW1[32];

  const int tid = threadIdx.x;
  if (tid < NEXP) { sCnt[tid] = 0; sSW[tid] = 0.0f; }
  __syncthreads();

  const int wave = tid >> 6;     // 0..7
  const int lane = tid & 63;
  const int n0 = blockIdx.x * 32 + wave * 4;   // this wave's 4 tokens

  const float cw = cwp[0];
  const float4* rw4 = (const float4*)rw;       // [e*256 + dp]

  const float4* x4[4];
  uint2* xgp[4];
#pragma unroll
  for (int t = 0; t < 4; ++t) {
    x4[t]  = (const float4*)(x + (size_t)(n0 + t) * DDIM);
    xgp[t] = (uint2*)(xg + (size_t)(n0 + t) * DDIM);
  }

  float p[4][NEXP];
#pragma unroll
  for (int t = 0; t < 4; ++t)
#pragma unroll
    for (int e = 0; e < NEXP; ++e) p[t][e] = 0.0f;

#pragma unroll
  for (int it = 0; it < 4; ++it) {
    const int dp = lane + 64 * it;             // float4 index (256 per row)
    float4 wv[NEXP];
#pragma unroll
    for (int e = 0; e < NEXP; ++e) wv[e] = rw4[e * 256 + dp];
#pragma unroll
    for (int t = 0; t < 4; ++t) {
      float4 xv = x4[t][dp];
      uint2 pk;
      pk.x = (uint32_t)f2bf(xv.x) | ((uint32_t)f2bf(xv.y) << 16);
      pk.y = (uint32_t)f2bf(xv.z) | ((uint32_t)f2bf(xv.w) << 16);
      xgp[t][dp] = pk;
#pragma unroll
      for (int e = 0; e < NEXP; ++e)
        p[t][e] = fmaf(xv.x, wv[e].x,
                  fmaf(xv.y, wv[e].y,
                  fmaf(xv.z, wv[e].z,
                  fmaf(xv.w, wv[e].w, p[t][e]))));
    }
  }

#pragma unroll
  for (int t = 0; t < 4; ++t)
#pragma unroll
    for (int e = 0; e < NEXP; ++e) {
#pragma unroll
      for (int off = 32; off > 0; off >>= 1)
        p[t][e] += __shfl_xor(p[t][e], off, 64);
    }

  float lsw[NEXP];
#pragma unroll
  for (int e = 0; e < NEXP; ++e) lsw[e] = 0.0f;

#pragma unroll
  for (int t = 0; t < 4; ++t) {
    const int i = wave * 4 + t;                // token slot in block (0..31)
    if (lane == 0) {
      float w[NEXP];
      float m = -1e30f;
#pragma unroll
      for (int e = 0; e < NEXP; ++e) {
        w[e] = p[t][e] + rb[e] + cw * cv[e];
        m = fmaxf(m, w[e]);
      }
      float s = 0.0f;
#pragma unroll
      for (int e = 0; e < NEXP; ++e) { w[e] = expf(w[e] - m); s += w[e]; }
      float inv = 1.0f / s;
#pragma unroll
      for (int e = 0; e < NEXP; ++e) { w[e] *= inv; lsw[e] += w[e]; }
      int e0 = 0;
#pragma unroll
      for (int e = 1; e < NEXP; ++e) if (w[e] > w[e0]) e0 = e;
      int e1 = (e0 == 0) ? 1 : 0;
#pragma unroll
      for (int e = 0; e < NEXP; ++e) if (e != e0 && w[e] > w[e1]) e1 = e;
      float rsum = 1.0f / (w[e0] + w[e1]);
      int r0 = atomicAdd(&sCnt[e0], 1);
      int r1 = atomicAdd(&sCnt[e1], 1);
      sE0[i] = e0; sE1[i] = e1; sR0[i] = r0; sR1[i] = r1;
      sW0[i] = w[e0] * rsum; sW1[i] = w[e1] * rsum;
    }
  }

  if (lane == 0) {
#pragma unroll
    for (int e = 0; e < NEXP; ++e) atomicAdd(&sSW[e], lsw[e]);
  }
  __syncthreads();

  if (tid < NEXP) {
    sBase[tid] = atomicAdd(&cnt[tid * CNT_STRIDE], sCnt[tid]);
    atomicAdd(&sum_w[tid * CNT_STRIDE], sSW[tid]);
  }
  __syncthreads();

  if (tid < 64) {
    int i = tid >> 1, k = tid & 1;
    int e = k ? sE1[i] : sE0[i];
    int r = k ? sR1[i] : sR0[i];
    float wv = k ? sW1[i] : sW0[i];
    int pos = sBase[e] + r;
    int n = blockIdx.x * 32 + i;
    perm_idx[e * N_TOK + pos] = n;
    perm_w [e * N_TOK + pos] = wv;
    inv_idx[2 * n + k] = (e << 14) | pos;     // pos < 16384 fits 14 bits
  }

  // fused expert_w fp32->bf16 cast: E*D*D/4 = 2,097,152 float4 over
  // 512 blocks x 512 threads = 262,144 threads -> exactly 8 each.
  size_t base = (size_t)blockIdx.x * 512 + tid;
#pragma unroll
  for (int i2 = 0; i2 < 8; ++i2) {
    size_t idx = base + (size_t)i2 * 262144;
    float4 v = ew4[idx];
    wb4[idx] = make_ushort4(f2bf(v.x), f2bf(v.y), f2bf(v.z), f2bf(v.w));
  }
}

// ---- grouped GEMM, 256x256 tile, BK=64, 8 waves, double-buffered LDS,
//      2-phase pipeline (issue ALL of tile t+1's staging at the top of tile t,
//      one vmcnt(0)+s_barrier per K-tile).
// Block mapping (A-panel L2 co-location): hw = blockIdx.x; XCD = hw%8 (round
// robin). lid = (hw&7)*68 + (hw>>3) gives each XCD residue class 68
// CONSECUTIVE logical tiles; with lid = tileIdx*4 + tn the 4 tn-siblings
// sharing one A-panel are consecutive lids -> same XCD AND co-resident in the
// same dispatch window -> A-panel fetched ~once per XCD (was ~2-4x across
// rounds/XCDs). 544 = 8*68 exactly: bijective.
template<int MODE>
__global__ __launch_bounds__(512, 2) void moe_gemm_kernel(
    const unsigned short* __restrict__ xg, const unsigned short* __restrict__ wb,
    const float* __restrict__ eb,
    const int* __restrict__ perm_idx, const float* __restrict__ perm_w,
    const int* __restrict__ cnt,
    unsigned short* __restrict__ ybuf, float* __restrict__ out)
{
  const int hw = blockIdx.x;
  const int lid = (hw & 7) * (MAX_TILES * 4 / 8) + (hw >> 3);   // 68 per XCD
  const int tileIdx = lid >> 2;
  const int tn = lid & 3;

  int e = -1, tm = 0, count = 0, ebase = 0, pref = 0;
#pragma unroll
  for (int j = 0; j < NEXP; ++j) {
    int c = cnt[j * CNT_STRIDE];
    int t = (c + BM - 1) >> 8;
    if (e < 0 && tileIdx < pref + t) { e = j; tm = tileIdx - pref; count = c; }
    if (e < 0) ebase += c;
    pref += t;
  }
  if (e < 0) return;

  __shared__ struct { __bf16 As[2][BM * BK]; __bf16 Bs[2][BN * BK]; } sm;  // 128KB
  __shared__ int   tokS[BM];
  __shared__ float wtS[BM];

  const int tid = threadIdx.x;
  const int wave = tid >> 6;     // 0..7
  const int lane = tid & 63;

  if (tid < BM) {
    int row = tm * BM + tid;
    int rc = row < count ? row : count - 1;
    tokS[tid] = perm_idx[e * N_TOK + rc];
    wtS[tid] = (row < count) ? perm_w[e * N_TOK + row] : 0.0f;
  }
  __syncthreads();

  // staging: each half (128 rows) covered as wave -> 16 rows (2 calls x 8 rows);
  // lane -> row base + (l>>3), chunk slot s = l&7; LDS[r][s] holds global
  // chunk s^(r&7) (chunk = 16B of the 128B row). r&7 == (lane>>3)&7 for all halves.
  const unsigned short* wbase = wb + (size_t)e * DDIM * DDIM;
  const int rl = wave * 16 + (lane >> 3);
  const int cg = (((lane & 7) ^ (lane >> 3)) & 7) * 8;

  const unsigned short* gA[2][2];
  const unsigned short* gB[2][2];
#pragma unroll
  for (int h = 0; h < 2; ++h)
#pragma unroll
    for (int j = 0; j < 2; ++j) {
      gA[h][j] = xg + (size_t)tokS[h * 128 + rl + j * 8] * DDIM + cg;
      gB[h][j] = wbase + (size_t)(tn * BN + h * 128 + rl + j * 8) * DDIM + cg;
    }

#define STG_A(h, bsel) do { \
    load_lds16(gA[h][0], &sm.As[bsel][((h) * 128 + wave * 16) * BK]);     gA[h][0] += BK; \
    load_lds16(gA[h][1], &sm.As[bsel][((h) * 128 + wave * 16 + 8) * BK]); gA[h][1] += BK; \
  } while (0)
#define STG_B(h, bsel) do { \
    load_lds16(gB[h][0], &sm.Bs[bsel][((h) * 128 + wave * 16) * BK]);     gB[h][0] += BK; \
    load_lds16(gB[h][1], &sm.Bs[bsel][((h) * 128 + wave * 16 + 8) * BK]); gB[h][1] += BK; \
  } while (0)

  // prologue: stage tile 0 into buf 0, full drain once.
  STG_A(0, 0); STG_A(1, 0); STG_B(0, 0); STG_B(1, 0);
  BAR_VM0();

  const int wr = wave >> 2;          // 0..1 -> 128-row slab
  const int wc = wave & 3;           // 0..3 -> 64-col slab
  const int quad = lane >> 4;
  const int l15 = lane & 15;
  // frag read: row r, k-slot slot = (ks*4+quad) ^ (r&7); r&7 == l15&7.
  const int sl0 = (quad ^ (l15 & 7)) * 8;              // ks=0 slot offset (elems)
  const int rowA = (wr * 128 + l15) * BK + sl0;        // ^32 flips to ks=1
  const int rowB = (wc * 64 + l15) * BK + sl0;

  f32x4 acc[8][4] = {};   // acc[mi][ni]: rows wr*128+mi*16+l15, cols wc*64+ni*16+quad*4+reg

#pragma unroll
  for (int t = 0; t < NKT; ++t) {
    const int b = t & 1, nb = b ^ 1;
    const __bf16* Ab = sm.As[b];
    const __bf16* Bb = sm.Bs[b];

    // issue ALL of tile t+1's staging up front (8 gload_lds/thread) — these
    // have the entire compute of tile t (24 ds_read + 64 MFMA/wave) to land.
    if (t + 1 < NKT) { STG_A(0, nb); STG_A(1, nb); STG_B(0, nb); STG_B(1, nb); }

    bf16x8 Bf[4][2];
#pragma unroll
    for (int ni = 0; ni < 4; ++ni)
#pragma unroll
      for (int ks = 0; ks < 2; ++ks)
        Bf[ni][ks] = *(const bf16x8*)&Bb[(rowB + ni * 1024) ^ (ks * 32)];

#pragma unroll
    for (int mi = 0; mi < 8; ++mi) {
      bf16x8 a0 = *(const bf16x8*)&Ab[(rowA + mi * 1024)];
      bf16x8 a1 = *(const bf16x8*)&Ab[(rowA + mi * 1024) ^ 32];
#pragma unroll
      for (int ni = 0; ni < 4; ++ni) {
        acc[mi][ni] = __builtin_amdgcn_mfma_f32_16x16x32_bf16(Bf[ni][0], a0, acc[mi][ni], 0, 0, 0);
        acc[mi][ni] = __builtin_amdgcn_mfma_f32_16x16x32_bf16(Bf[ni][1], a1, acc[mi][ni], 0, 0, 0);
      }
    }

    // one barrier per K-tile. NO barrier after the final tile: all loads
    // drained at t=NKT-2's vmcnt(0), and the epilogue slab lives in buf0
    // (free while t=NKT-1 computes from buf1) -> waves flow straight from
    // their last MFMA into staggered epilogues.
    if (t + 1 < NKT) BAR_VM0();
  }

#undef STG_A
#undef STG_B

  const int valid = count - tm * BM;
  const int gb = ebase + tm * BM;

  if (MODE == 1) {
    // repack through per-wave 8KB slab carved from buf0 (As[0] for waves 0-3,
    // Bs[0] for waves 4-7 — disjoint from buf1 which tile 15 read), then
    // fully-coalesced 16B stores. Pitch 64 ushorts with 16B-chunk XOR swizzle
    // (chunk ^= row&7) for bank spread. Per-wave private + in-order DS ops ->
    // no barriers needed anywhere in the epilogue.
    __bf16* slab = (wave < 4) ? &sm.As[0][wave * 4096]
                              : &sm.Bs[0][(wave - 4) * 4096];
#pragma unroll
    for (int p = 0; p < 2; ++p) {
#pragma unroll
      for (int mi4 = 0; mi4 < 4; ++mi4) {
        const int mi = p * 4 + mi4;
        const int row = mi4 * 16 + l15;
        float wt = wtS[wr * 128 + mi * 16 + l15];
#pragma unroll
        for (int ni = 0; ni < 4; ++ni) {
          int gcol = tn * BN + wc * 64 + ni * 16 + quad * 4;
          const float4 bv = *(const float4*)&eb[e * DDIM + gcol];
          ushort4 pk;
          pk.x = f2bf((acc[mi][ni][0] + bv.x) * wt);
          pk.y = f2bf((acc[mi][ni][1] + bv.y) * wt);
          pk.z = f2bf((acc[mi][ni][2] + bv.z) * wt);
          pk.w = f2bf((acc[mi][ni][3] + bv.w) * wt);
          // logical col = ni*16 + quad*4 -> chunk = ni*2 + (quad>>1), sub = (quad&1)*4
          *(ushort4*)&slab[(row << 6) +
                           ((((ni << 1) + (quad >> 1)) ^ (row & 7)) << 3) +
                           ((quad & 1) << 2)] = pk;
        }
      }
#pragma unroll
      for (int s = 0; s < 8; ++s) {
        int lrow = s * 8 + (lane >> 3);
        uint4 v = *(const uint4*)&slab[(lrow << 6) + (((lane & 7) ^ (lrow & 7)) << 3)];
        int brow = wr * 128 + p * 64 + lrow;
        if (brow < valid)
          *(uint4*)&ybuf[(size_t)(gb + brow) * DDIM + tn * BN + wc * 64 + (lane & 7) * 8] = v;
      }
    }
  } else {
    // atomic fallback (small-ws path) — touches no LDS post-loop.
#pragma unroll
    for (int mi = 0; mi < 8; ++mi) {
      int brow = wr * 128 + mi * 16 + l15;
      float wt = wtS[brow];
      int tok = tokS[brow];
      if (brow < valid) {
#pragma unroll
        for (int ni = 0; ni < 4; ++ni) {
          int gcol = tn * BN + wc * 64 + ni * 16 + quad * 4;
          const float4 bv = *(const float4*)&eb[e * DDIM + gcol];
          atomicAdd(out + (size_t)tok * DDIM + gcol + 0, (acc[mi][ni][0] + bv.x) * wt);
          atomicAdd(out + (size_t)tok * DDIM + gcol + 1, (acc[mi][ni][1] + bv.y) * wt);
          atomicAdd(out + (size_t)tok * DDIM + gcol + 2, (acc[mi][ni][2] + bv.z) * wt);
          atomicAdd(out + (size_t)tok * DDIM + gcol + 3, (acc[mi][ni][3] + bv.w) * wt);
        }
      }
    }
  }
}

// ---- combine: out[n] = y[g0] + y[g1] (weights+bias already folded),
//      with the load-balancing loss fused into block 0 (one fewer dispatch).
__global__ __launch_bounds__(256) void combine_kernel(
    const unsigned short* __restrict__ ybuf, const int* __restrict__ inv_idx,
    const int* __restrict__ cnt, const float* __restrict__ sum_w,
    float* __restrict__ out)
{
  if (blockIdx.x == 0 && threadIdx.x == 0) {
    float l = 0.0f;
#pragma unroll
    for (int e = 0; e < NEXP; ++e)
      l += sum_w[e * CNT_STRIDE] * (float)cnt[e * CNT_STRIDE];
    out[(size_t)N_TOK * DDIM] = l * (1.0f / ((float)N_TOK * (float)N_TOK));
  }

  const int wave = threadIdx.x >> 6;
  const int lane = threadIdx.x & 63;
  const int n = blockIdx.x * 4 + wave;

  int base[NEXP];
  int acc = 0;
#pragma unroll
  for (int j = 0; j < NEXP; ++j) { base[j] = acc; acc += cnt[j * CNT_STRIDE]; }

  int i0 = inv_idx[2 * n];
  int i1 = inv_idx[2 * n + 1];
  int g0 = base[i0 >> 14] + (i0 & 16383);
  int g1 = base[i1 >> 14] + (i1 & 16383);

  const uint4* r0 = (const uint4*)(ybuf + (size_t)g0 * DDIM);
  const uint4* r1 = (const uint4*)(ybuf + (size_t)g1 * DDIM);
  float4* o = (float4*)(out + (size_t)n * DDIM);

#pragma unroll
  for (int it = 0; it < 2; ++it) {
    int c = lane + 64 * it;
    uint4 a = r0[c];
    uint4 b = r1[c];
    float2 a0 = bfpair(a.x), a1 = bfpair(a.y), a2 = bfpair(a.z), a3 = bfpair(a.w);
    float2 b0 = bfpair(b.x), b1 = bfpair(b.y), b2 = bfpair(b.z), b3 = bfpair(b.w);
    float4 v0, v1;
    v0.x = a0.x + b0.x; v0.y = a0.y + b0.y; v0.z = a1.x + b1.x; v0.w = a1.y + b1.y;
    v1.x = a2.x + b2.x; v1.y = a2.y + b2.y; v1.z = a3.x + b3.x; v1.w = a3.y + b3.y;
    o[2 * c] = v0;
    o[2 * c + 1] = v1;
  }
}

__global__ void loss_kernel(const float* __restrict__ sum_w,
                            const int* __restrict__ cnt,
                            float* __restrict__ out) {
  if (threadIdx.x == 0 && blockIdx.x == 0) {
    float l = 0.0f;
#pragma unroll
    for (int e = 0; e < NEXP; ++e)
      l += sum_w[e * CNT_STRIDE] * (float)cnt[e * CNT_STRIDE];
    out[(size_t)N_TOK * DDIM] = l * (1.0f / ((float)N_TOK * (float)N_TOK));
  }
}

extern "C" void kernel_launch(void* const* d_in, const int* in_sizes, int n_in,
                              void* d_out, int out_size, void* d_ws, size_t ws_size,
                              hipStream_t stream) {
  const float* x  = (const float*)d_in[0];
  const float* cv = (const float*)d_in[1];
  const float* rw = (const float*)d_in[2];
  const float* rb = (const float*)d_in[3];
  const float* ew = (const float*)d_in[4];
  const float* eb = (const float*)d_in[5];
  const float* cw = (const float*)d_in[6];
  float* out = (float*)d_out;

  char* ws = (char*)d_ws;
  unsigned short* xg = (unsigned short*)ws;                       // N*D bf16   (33,554,432 B)
  unsigned short* wb = (unsigned short*)(ws + 33554432);          // E*D*D bf16 (16,777,216 B)
  int*   perm_idx = (int*)  (ws + 50331648);                      // E*N int    (524,288 B)
  float* perm_w   = (float*)(ws + 50855936);                      // E*N float  (524,288 B)
  int*   inv_idx  = (int*)  (ws + 51380224);                      // 2*N int    (131,072 B)
  int*   cnt      = (int*)  (ws + 51511296);                      // padded     (2,048 B)
  float* sum_w    = (float*)(ws + 51513344);                      // padded     (2,048 B)
  unsigned short* ybuf = (unsigned short*)(ws + 51515392);        // 2*N*D bf16 (67,108,864 B)
  const size_t NEED = 51515392ull + 67108864ull;

  const bool big = ws_size >= NEED;

  hipMemsetAsync(cnt, 0, 4096, stream);                           // cnt + sum_w (padded)
  if (!big)
    hipMemsetAsync(d_out, 0, (size_t)N_TOK * DDIM * sizeof(float), stream);

  router_kernel<<<N_TOK / 32, 512, 0, stream>>>(x, rw, rb, cv, cw,
                                                (const float4*)ew, (ushort4*)wb,
                                                xg, perm_idx, perm_w, inv_idx, cnt, sum_w);

  if (big) {
    moe_gemm_kernel<1><<<MAX_TILES * 4, 512, 0, stream>>>(
        xg, wb, eb, perm_idx, perm_w, cnt, ybuf, out);
    combine_kernel<<<N_TOK / 4, 256, 0, stream>>>(ybuf, inv_idx, cnt, sum_w, out);
  } else {
    moe_gemm_kernel<0><<<MAX_TILES * 4, 512, 0, stream>>>(
        xg, wb, eb, perm_idx, perm_w, cnt, ybuf, out);
    loss_kernel<<<1, 64, 0, stream>>>(sum_w, cnt, out);
  }
}